// Round 15
// baseline (468.614 us; speedup 1.0000x reference)
//
#include <hip/hip_runtime.h>

#define HSZ 32
#define SEQ 1024

__device__ __forceinline__ float fast_rcp(float v) { return __builtin_amdgcn_rcpf(v); }

__device__ __forceinline__ float sigmoidf_(float v) {
    return fast_rcp(1.0f + __expf(-v));
}
__device__ __forceinline__ float tanhf_(float v) {
    return fmaf(2.0f, sigmoidf_(2.0f * v), -1.0f);
}

// sum within each 16-lane row on the VALU pipe (DPP row_ror) -- proven r13/r14
template <int N>
__device__ __forceinline__ float row_ror_add(float p) {
    const int t = __builtin_amdgcn_update_dpp(0, __float_as_int(p), 0x120 | N, 0xF, 0xF, true);
    return p + __int_as_float(t);
}
// xor-16 swizzle ISSUE (result consumed one step later -- latency hidden; r14-proven)
__device__ __forceinline__ float swz16(float p) {
    return __int_as_float(__builtin_amdgcn_ds_swizzle(__float_as_int(p), 0x401F));
}
// wave-uniform broadcast of lane k's h -> SGPR (free FMA operand)
__device__ __forceinline__ float rl(float v, int k) {
    return __int_as_float(__builtin_amdgcn_readlane(__float_as_int(v), k));
}

// r15: ONE batch per wave (2048 waves = 2/SIMD), r10's proven 2-row layout:
// low lanes u own rows u (i), u+32 (f); high lanes own u+64 (g), u+96 (o);
// one shfl_xor(32) pair exchanges gates; h ends replicated in lanes u,u+32.
// NEW: h broadcast via 32x v_readlane -> SGPRs. NO LDS in the loop at all:
// no write, no read, no round-trip stall, no hp registers. W demand 64 regs,
// total ~116 < 128 -> genuinely fits, no AGPR parking copies (r6-r14's tax).
// Attention: r14-proven DPP row_ror + deferred xor16 swizzle. __expf kept
// everywhere (r2's failure is now attributed to exp2-constant drift).
__global__ __launch_bounds__(64)
__attribute__((amdgpu_waves_per_eu(2, 2)))
void lstm_attn_fused(const float* __restrict__ x,
                     const float* __restrict__ W_ih,
                     const float* __restrict__ W_hh,
                     const float* __restrict__ b_ih,
                     const float* __restrict__ b_hh,
                     const float* __restrict__ attn_w,
                     const float* __restrict__ fc1_w,
                     const float* __restrict__ fc1_b,
                     const float* __restrict__ fc2_w,
                     const float* __restrict__ fc2_b,
                     float* __restrict__ out)
{
    const int lane = threadIdx.x;        // 0..63
    const int u    = lane & 31;          // hidden unit owned by this lane
    const bool low = lane < 32;
    const int b    = blockIdx.x;         // batch element
    const int r0   = u + (low ? 0 : 64); // row of gate A (i or g)
    const int r1   = r0 + 32;            // row of gate B (f or o)

    // ---- preload weights: 2 gate rows per lane (64 scalars) ----
    float w0[HSZ], w1[HSZ];
#pragma unroll
    for (int k = 0; k < HSZ; ++k) {
        w0[k] = W_hh[r0 * HSZ + k];
        w1[k] = W_hh[r1 * HSZ + k];
    }
    float wi0[3], wi1[3];
#pragma unroll
    for (int j = 0; j < 3; ++j) {
        wi0[j] = W_ih[r0 * 3 + j];
        wi1[j] = W_ih[r1 * 3 + j];
    }
    float b0 = b_ih[r0] + b_hh[r0];
    float b1 = b_ih[r1] + b_hh[r1];
    float aw = attn_w[u];

    // Pin loop-invariants (asm defs can't be rematerialized from memory).
#pragma unroll
    for (int k = 0; k < HSZ; ++k) {
        asm volatile("" : "+v"(w0[k]), "+v"(w1[k]));
    }
#pragma unroll
    for (int j = 0; j < 3; ++j) {
        asm volatile("" : "+v"(wi0[j]), "+v"(wi1[j]));
    }
    asm volatile("" : "+v"(b0), "+v"(b1), "+v"(aw));

    // gate-A nonlinearity: low -> sigmoid (i); high -> tanh (g) = 2*sig(2x)-1
    const float nsS = low ? 1.0f : 2.0f;
    const float nsA = low ? 1.0f : 2.0f;
    const float nsB = low ? 0.0f : -1.0f;

    float c = 0.0f, h = 0.0f;
    float Pacc = 0.0f, lacc = 0.0f;      // online softmax pooling (scores bounded ~5.7)
    float p_prev = 0.0f, sv_prev = 0.0f; // deferred attention state

    const float4* __restrict__ xv = (const float4*)(x + (size_t)b * SEQ * 3);

    auto step = [&](float x0, float x1, float x2, float accum) {
        // ---- broadcast h_{t-1} to SGPRs (32 independent readlanes) ----
        float hs[HSZ];
#pragma unroll
        for (int k = 0; k < HSZ; ++k) hs[k] = rl(h, k);

        // ---- matvec: 2 rows x two independent 16-deep chains, SGPR operands ----
        float a00 = fmaf(wi0[0], x0, fmaf(wi0[1], x1, fmaf(wi0[2], x2, b0)));
        float a10 = fmaf(wi1[0], x0, fmaf(wi1[1], x1, fmaf(wi1[2], x2, b1)));
        float a01 = 0.0f, a11 = 0.0f;
#pragma unroll
        for (int k = 0; k < 16; ++k) {
            a00 = fmaf(w0[k],      hs[k],      a00);
            a01 = fmaf(w0[k + 16], hs[k + 16], a01);
            a10 = fmaf(w1[k],      hs[k],      a10);
            a11 = fmaf(w1[k + 16], hs[k + 16], a11);
        }

        // ---- deferred attention finish for h_{t-1} (h reg still holds it) ----
        {
            const float pf  = p_prev + sv_prev;            // swizzle long returned
            const float wgt = accum * __expf(fmaxf(pf, 0.0f));
            lacc += wgt;
            Pacc = fmaf(wgt, h, Pacc);
        }

        // ---- nonlinearities: v0 = i (low) / g (high); v1 = f (low) / o (high) ----
        const float v0 = fmaf(nsA, sigmoidf_(nsS * (a00 + a01)), nsB);
        const float v1 = sigmoidf_(a10 + a11);

        // exchange with the partner half (one xor-32 pair)
        const float e0 = __shfl_xor(v0, 32);
        const float e1 = __shfl_xor(v1, 32);
        const float i_ = low ? v0 : e0;
        const float f_ = low ? v1 : e1;
        const float g_ = low ? e0 : v0;
        const float o_ = low ? e1 : v1;

        c = fmaf(f_, c, i_ * g_);
        h = o_ * tanhf_(c);              // replicated in lanes u and u+32

        // ---- attention row-reduce on the VALU pipe; xor16 issued, consumed next step ----
        float p = h * aw;
        p = row_ror_add<1>(p);
        p = row_ror_add<2>(p);
        p = row_ror_add<4>(p);
        p = row_ror_add<8>(p);           // 16-row sums
        sv_prev = swz16(p);              // in-flight across the next matvec
        p_prev  = p;
    };

    // x software pipeline: prefetch next 4-step group while computing current
    float4 xa = xv[0], xb = xv[1], xc = xv[2];
    for (int s0 = 0; s0 < SEQ; s0 += 4) {
        const int nfi = ((s0 + 4) < SEQ) ? (((s0 + 4) * 3) >> 2) : 0;
        const float4 na = xv[nfi], nb = xv[nfi + 1], nc = xv[nfi + 2];
        step(xa.x, xa.y, xa.z, (s0 == 0) ? 0.0f : 1.0f);   // mask phantom first finish
        step(xa.w, xb.x, xb.y, 1.0f);
        step(xb.z, xb.w, xc.x, 1.0f);
        step(xc.y, xc.z, xc.w, 1.0f);
        xa = na; xb = nb; xc = nc;
    }
    // tail: finish the last step's attention (h = h_SEQ)
    {
        const float pf  = p_prev + sv_prev;
        const float wgt = __expf(fmaxf(pf, 0.0f));
        lacc += wgt;
        Pacc = fmaf(wgt, h, Pacc);
    }

    // ---- epilogue: pooled -> fc1(relu) -> fc2 (single wave, in-order DS, no barriers) ----
    __shared__ float pool[64];
    __shared__ float h1sh[16];
    pool[lane] = Pacc * fast_rcp(lacc);  // slots 0..31 authoritative

    {
        const int j = lane & 15;         // fc1 row (computed redundantly by 4 lanes)
        float acc = fc1_b[j];
#pragma unroll
        for (int k = 0; k < HSZ; ++k)
            acc = fmaf(fc1_w[j * HSZ + k], pool[k], acc);
        if (lane < 16) h1sh[j] = fmaxf(acc, 0.0f);

        if (lane < 2) {
            float acc2 = fc2_b[lane];
#pragma unroll
            for (int m = 0; m < 16; ++m)
                acc2 = fmaf(fc2_w[lane * 16 + m], h1sh[m], acc2);
            out[b * 2 + lane] = acc2;
        }
    }
}

extern "C" void kernel_launch(void* const* d_in, const int* in_sizes, int n_in,
                              void* d_out, int out_size, void* d_ws, size_t ws_size,
                              hipStream_t stream) {
    const float* x      = (const float*)d_in[0];
    const float* W_ih   = (const float*)d_in[1];
    const float* W_hh   = (const float*)d_in[2];
    const float* b_ih   = (const float*)d_in[3];
    const float* b_hh   = (const float*)d_in[4];
    const float* attn_w = (const float*)d_in[5];
    const float* fc1_w  = (const float*)d_in[6];
    const float* fc1_b  = (const float*)d_in[7];
    const float* fc2_w  = (const float*)d_in[8];
    const float* fc2_b  = (const float*)d_in[9];

    const int B = in_sizes[0] / (SEQ * 3);   // 2048

    lstm_attn_fused<<<dim3(B), dim3(64), 0, stream>>>(
        x, W_ih, W_hh, b_ih, b_hh, attn_w, fc1_w, fc1_b, fc2_w, fc2_b,
        (float*)d_out);
}

// Round 16
// 326.039 us; speedup vs baseline: 1.4373x; 1.4373x over previous
//
#include <hip/hip_runtime.h>

#define HSZ 32
#define SEQ 1024

typedef float v2f __attribute__((ext_vector_type(2)));

__device__ __forceinline__ float fast_rcp(float v) { return __builtin_amdgcn_rcpf(v); }

__device__ __forceinline__ float sigmoidf_(float v) {
    return fast_rcp(1.0f + __expf(-v));
}
__device__ __forceinline__ float tanhf_(float v) {
    return fmaf(2.0f, sigmoidf_(2.0f * v), -1.0f);
}

// sum within each 16-lane row on the VALU pipe (DPP row_ror) -- proven r13/r14
template <int N>
__device__ __forceinline__ float row_ror_add(float p) {
    const int t = __builtin_amdgcn_update_dpp(0, __float_as_int(p), 0x120 | N, 0xF, 0xF, true);
    return p + __int_as_float(t);
}
// xor-16 swizzle ISSUE (result consumed one step later -- latency hidden; r14-proven)
__device__ __forceinline__ float swz16(float p) {
    return __int_as_float(__builtin_amdgcn_ds_swizzle(__float_as_int(p), 0x401F));
}

// r16 = r14 (best: 368us) with ONE scheduling change: the deferred-attention
// FINISH (exp + accumulates; independent of hp) moves from after the matvec
// to BEFORE it. The hp reads issued at the previous step's tail get ~40 more
// cycles of independent work before the matvec's first consume -> less of the
// ~150-260cy LDS round-trip latency is exposed (nothing else hides it at
// 1 wave/SIMD). All math byte-identical to r14.
__global__ __launch_bounds__(64)
__attribute__((amdgpu_waves_per_eu(1, 1)))
void lstm_attn_fused(const float* __restrict__ x,
                     const float* __restrict__ W_ih,
                     const float* __restrict__ W_hh,
                     const float* __restrict__ b_ih,
                     const float* __restrict__ b_hh,
                     const float* __restrict__ attn_w,
                     const float* __restrict__ fc1_w,
                     const float* __restrict__ fc1_b,
                     const float* __restrict__ fc2_w,
                     const float* __restrict__ fc2_b,
                     float* __restrict__ out)
{
    const int lane = threadIdx.x;        // 0..63
    const int half = lane >> 5;          // which batch element of this block
    const int u    = lane & 31;          // hidden unit owned by this lane
    const int bsel = blockIdx.x * 2 + half;

    // ---- preload weights: 4 gate rows per lane, v2 packed ----
    const v2f* __restrict__ Whv = (const v2f*)W_hh;      // [128][16] v2f
    v2f wI[16], wF[16], wG[16], wO[16];
#pragma unroll
    for (int k = 0; k < 16; ++k) {
        wI[k] = Whv[(u      ) * 16 + k];
        wF[k] = Whv[(u + 32 ) * 16 + k];
        wG[k] = Whv[(u + 64 ) * 16 + k];
        wO[k] = Whv[(u + 96 ) * 16 + k];
    }
    float wiI[3], wiF[3], wiG[3], wiO[3];
#pragma unroll
    for (int j = 0; j < 3; ++j) {
        wiI[j] = W_ih[(u      ) * 3 + j];
        wiF[j] = W_ih[(u + 32 ) * 3 + j];
        wiG[j] = W_ih[(u + 64 ) * 3 + j];
        wiO[j] = W_ih[(u + 96 ) * 3 + j];
    }
    float bI = b_ih[u     ] + b_hh[u     ];
    float bF = b_ih[u + 32] + b_hh[u + 32];
    float bG = b_ih[u + 64] + b_hh[u + 64];
    float bO = b_ih[u + 96] + b_hh[u + 96];
    float aw = attn_w[u];

    // Pin loop-invariants (asm defs can't be rematerialized from memory).
#pragma unroll
    for (int k = 0; k < 16; ++k) {
        asm volatile("" : "+v"(wI[k]), "+v"(wF[k]), "+v"(wG[k]), "+v"(wO[k]));
    }
#pragma unroll
    for (int j = 0; j < 3; ++j) {
        asm volatile("" : "+v"(wiI[j]), "+v"(wiF[j]), "+v"(wiG[j]), "+v"(wiO[j]));
    }
    asm volatile("" : "+v"(bI), "+v"(bF), "+v"(bG), "+v"(bO), "+v"(aw));

    // h state: [0..31]=half0, [32..63]=half1. Single-wave blocks, DS in-order
    // per wave -> no barriers anywhere (r7-proven).
    __shared__ float hbuf[64];
    hbuf[lane] = 0.0f;
    const v2f* __restrict__ hb2 = (const v2f*)hbuf + (half << 4);

    float c = 0.0f, h = 0.0f;
    float Pacc = 0.0f, lacc = 0.0f;      // online softmax pooling (scores bounded ~5.7)
    float p_prev = 0.0f, sv_prev = 0.0f; // deferred attention: row-sum + in-flight swizzle

    const float4* __restrict__ xv = (const float4*)(x + (size_t)bsel * SEQ * 3);

    // hp regs hold h_{t-1}; h0 = 0 (no LDS read needed for step 1).
    v2f hp[16];
#pragma unroll
    for (int k = 0; k < 16; ++k) { hp[k].x = 0.0f; hp[k].y = 0.0f; }

    auto step = [&](float x0, float x1, float x2, float accum) {
        // ---- deferred attention finish for h_{t-1} FIRST: independent of hp,
        // so the in-flight hp reads get this window before the matvec consumes ----
        {
            const float pf  = p_prev + sv_prev;            // swizzle long returned
            const float wgt = accum * __expf(fmaxf(pf, 0.0f));
            lacc += wgt;
            Pacc = fmaf(wgt, h, Pacc);
        }

        // ---- input projection (also hp-independent; more cover) ----
        v2f aI; aI.x = fmaf(wiI[0],x0, fmaf(wiI[1],x1, fmaf(wiI[2],x2, bI))); aI.y = 0.0f;
        v2f aF; aF.x = fmaf(wiF[0],x0, fmaf(wiF[1],x1, fmaf(wiF[2],x2, bF))); aF.y = 0.0f;
        v2f aG; aG.x = fmaf(wiG[0],x0, fmaf(wiG[1],x1, fmaf(wiG[2],x2, bG))); aG.y = 0.0f;
        v2f aO; aO.x = fmaf(wiO[0],x0, fmaf(wiO[1],x1, fmaf(wiO[2],x2, bO))); aO.y = 0.0f;

        // ---- matvec: first hp consumption ----
#pragma unroll
        for (int k = 0; k < 16; ++k) {
            aI = __builtin_elementwise_fma(wI[k], hp[k], aI);
            aF = __builtin_elementwise_fma(wF[k], hp[k], aF);
            aG = __builtin_elementwise_fma(wG[k], hp[k], aG);
            aO = __builtin_elementwise_fma(wO[k], hp[k], aO);
        }

        // ---- gates: all lane-local ----
        const float i_ = sigmoidf_(aI.x + aI.y);
        const float f_ = sigmoidf_(aF.x + aF.y);
        const float g_ = tanhf_   (aG.x + aG.y);
        const float o_ = sigmoidf_(aO.x + aO.y);

        c = fmaf(f_, c, i_ * g_);
        h = o_ * tanhf_(c);

        hbuf[lane] = h;                  // publish h_t

        // prefetch h_t for the NEXT step (in-order DS: reads see the write)
#pragma unroll
        for (int k = 0; k < 16; ++k) hp[k] = hb2[k];

        // ---- attention row-reduce on the VALU pipe (fills DS-read wait) ----
        float p = h * aw;
        p = row_ror_add<1>(p);
        p = row_ror_add<2>(p);
        p = row_ror_add<4>(p);
        p = row_ror_add<8>(p);           // every lane in its 16-row has row sum
        sv_prev = swz16(p);              // ISSUE xor16; consumed next step
        p_prev  = p;
    };

    // x software pipeline: prefetch next 4-step group while computing current
    float4 xa = xv[0], xb = xv[1], xc = xv[2];
    for (int s0 = 0; s0 < SEQ; s0 += 4) {
        const int nfi = ((s0 + 4) < SEQ) ? (((s0 + 4) * 3) >> 2) : 0;
        const float4 na = xv[nfi], nb = xv[nfi + 1], nc = xv[nfi + 2];
        step(xa.x, xa.y, xa.z, (s0 == 0) ? 0.0f : 1.0f);   // mask phantom first finish
        step(xa.w, xb.x, xb.y, 1.0f);
        step(xb.z, xb.w, xc.x, 1.0f);
        step(xc.y, xc.z, xc.w, 1.0f);
        xa = na; xb = nb; xc = nc;
    }
    // tail: finish the last step's attention (h = h_SEQ)
    {
        const float pf  = p_prev + sv_prev;
        const float wgt = __expf(fmaxf(pf, 0.0f));
        lacc += wgt;
        Pacc = fmaf(wgt, h, Pacc);
    }

    // ---- epilogue: pooled -> fc1(relu) -> fc2, per half (no barriers) ----
    hbuf[lane] = Pacc * fast_rcp(lacc);  // pooled[u] of this half's batch

    {
        const int j = lane & 15;         // fc1 row (lanes 16..31 redundant)
        const float* __restrict__ hb = hbuf + (half << 5);
        float acc = fc1_b[j];
#pragma unroll
        for (int k = 0; k < HSZ; ++k)
            acc = fmaf(fc1_w[j * HSZ + k], hb[k], acc);
        __shared__ float h1sh[2][16];
        if ((lane & 31) < 16) h1sh[half][j] = fmaxf(acc, 0.0f);

        if ((lane & 31) < 2) {
            const int oi = lane & 31;
            float acc2 = fc2_b[oi];
#pragma unroll
            for (int m = 0; m < 16; ++m)
                acc2 = fmaf(fc2_w[oi * 16 + m], h1sh[half][m], acc2);
            out[bsel * 2 + oi] = acc2;
        }
    }
}

extern "C" void kernel_launch(void* const* d_in, const int* in_sizes, int n_in,
                              void* d_out, int out_size, void* d_ws, size_t ws_size,
                              hipStream_t stream) {
    const float* x      = (const float*)d_in[0];
    const float* W_ih   = (const float*)d_in[1];
    const float* W_hh   = (const float*)d_in[2];
    const float* b_ih   = (const float*)d_in[3];
    const float* b_hh   = (const float*)d_in[4];
    const float* attn_w = (const float*)d_in[5];
    const float* fc1_w  = (const float*)d_in[6];
    const float* fc1_b  = (const float*)d_in[7];
    const float* fc2_w  = (const float*)d_in[8];
    const float* fc2_b  = (const float*)d_in[9];

    const int B = in_sizes[0] / (SEQ * 3);   // 2048

    lstm_attn_fused<<<dim3(B / 2), dim3(64), 0, stream>>>(
        x, W_ih, W_hh, b_ih, b_hh, attn_w, fc1_w, fc1_b, fc2_w, fc2_b,
        (float*)d_out);
}